// Round 4
// baseline (179.198 us; speedup 1.0000x reference)
//
#include <hip/hip_runtime.h>
#include <math.h>

// DeepFeatureLoss: B=2, N=4096, D=32, fp32 in/out.
// out[0..1] = ce_loss[b], out[2..3] = reg_loss[b].
//
// ce_i = log(s_f) - t/s_p   (softmax max pinned at 0; both dists <= 0):
//   s_p = sum_j exp(pd_ij), t = sum_j exp(pd_ij)*fd_ij, s_f = sum_j exp(fd_ij)
// exp2 folding: points *PSC, features *FSC, norms *L2E -> bare v_exp_f32;
// t is in log2 units -> *LN2 at finalize.
//
// R4 structure: 2 kernels.
//  kA: zero acc/cnt/out; pack LANE-ORDERED f16 fragments for BOTH f1 (A) and
//      f2 (B): slot kb*16+c, so main-kernel lane l reads frag[tile*64+l]
//      (contiguous 1KB per wave). Also pp1/pp2 = (p*PSC, n*L2E).
//  kB: per (i-group, chunk) block: 16 MFMAs + fused softmax-sums, column
//      reduce via shfl_xor, atomicAdd into acc planes; arrival counter per
//      i-group (ACQ_REL agent scope); last of 16 blocks finalizes its 64 rows
//      (ce + reg) and atomicAdds out.
//
// ws (floats): pp1[0,32768) pp2[32768,65536) fragB[65536,196608)
// fragA[196608,327680) accS[327680,+8192) accT accF cnt(u32)@352256.

#define NPTS 4096
#define BATCH 2
#define DF 32
#define ROWS_TOT 8192
#define NCHUNK 16
#define NGROUP 128               // i-groups of 64 rows

#define L2E  1.4426950408889634f
#define LN2  0.6931471805599453f
#define FSC  1.6986436f          // sqrt(2*log2e)
#define PSC  240.2244f           // 200*sqrt(log2e)

typedef _Float16 half8 __attribute__((ext_vector_type(8)));
typedef float f4 __attribute__((ext_vector_type(4)));

// ---- kA: prep + zero ----
__global__ void kA_prep(const float* __restrict__ pts,
                        const float* __restrict__ f1g,
                        const float* __restrict__ f2g,
                        float* __restrict__ pp1, float* __restrict__ pp2,
                        _Float16* __restrict__ fragA, _Float16* __restrict__ fragB,
                        float* __restrict__ accS, float* __restrict__ accT,
                        float* __restrict__ accF, unsigned* __restrict__ cnt,
                        float* __restrict__ out) {
    const int r = blockIdx.x * 64 + threadIdx.x;     // 0..8191
    accS[r] = 0.0f; accT[r] = 0.0f; accF[r] = 0.0f;
    if (r < NGROUP) cnt[r] = 0u;
    if (r < 4) out[r] = 0.0f;

    const int b = r >> 12, local = r & (NPTS - 1);
    const int jt = (b << 8) + (local >> 4);          // global tile id 0..511
    const int c  = local & 15;                       // row/col within tile

    float n1 = 0.0f, n2 = 0.0f;
    {
        const float4* f2v = (const float4*)(f2g + (size_t)r * DF);
        float vals[32];
#pragma unroll
        for (int q = 0; q < 8; ++q) {
            float4 v = f2v[q];
            vals[4*q]=v.x; vals[4*q+1]=v.y; vals[4*q+2]=v.z; vals[4*q+3]=v.w;
            n2 += v.x*v.x + v.y*v.y + v.z*v.z + v.w*v.w;
        }
        half8* fv = (half8*)fragB;
#pragma unroll
        for (int kb = 0; kb < 4; ++kb) {             // lane-ordered slot
            half8 h;
#pragma unroll
            for (int i = 0; i < 8; ++i) h[i] = (_Float16)(vals[kb*8+i] * FSC);
            fv[(size_t)jt*64 + kb*16 + c] = h;
        }
    }
    {
        const float4* f1v = (const float4*)(f1g + (size_t)r * DF);
        float vals[32];
#pragma unroll
        for (int q = 0; q < 8; ++q) {
            float4 v = f1v[q];
            vals[4*q]=v.x; vals[4*q+1]=v.y; vals[4*q+2]=v.z; vals[4*q+3]=v.w;
            n1 += v.x*v.x + v.y*v.y + v.z*v.z + v.w*v.w;
        }
        half8* fv = (half8*)fragA;
#pragma unroll
        for (int kb = 0; kb < 4; ++kb) {
            half8 h;
#pragma unroll
            for (int i = 0; i < 8; ++i) h[i] = (_Float16)(vals[kb*8+i] * FSC);
            fv[(size_t)jt*64 + kb*16 + c] = h;
        }
    }
    const float* pp = pts + (size_t)r * 3;
    const float px = pp[0]*PSC, py = pp[1]*PSC, pz = pp[2]*PSC;
    ((float4*)pp1)[r] = make_float4(px, py, pz, n1 * L2E);
    ((float4*)pp2)[r] = make_float4(px, py, pz, n2 * L2E);
}

// ---- kB: main + last-block finalize ----
__launch_bounds__(256)
__global__ void kB_main(const float* __restrict__ pp1,
                        const float* __restrict__ pp2,
                        const _Float16* __restrict__ fragA,
                        const _Float16* __restrict__ fragB,
                        const float* __restrict__ f1g,
                        const float* __restrict__ f2g,
                        const float* __restrict__ wg,
                        float* __restrict__ accS, float* __restrict__ accT,
                        float* __restrict__ accF, unsigned* __restrict__ cnt,
                        float* __restrict__ out) {
    const int tid = threadIdx.x;
    const int l = tid & 63, wv = tid >> 6;
    const int chunk = blockIdx.x & 15;
    const int ig    = blockIdx.x >> 4;               // 0..127
    const int i_tile = ig * 4 + wv;                  // 0..511
    const int b = i_tile >> 8;
    const int i0g = b * NPTS + (i_tile & 255) * 16;
    const int lr = l & 15, lk = l >> 4;

    const half8 afrag = ((const half8*)fragA)[(size_t)i_tile * 64 + l];

    const int rbase = i0g + lk * 4;                  // this lane's 4 rows
    const float4 q0 = ((const float4*)pp1)[rbase + 0];
    const float4 q1 = ((const float4*)pp1)[rbase + 1];
    const float4 q2 = ((const float4*)pp1)[rbase + 2];
    const float4 q3 = ((const float4*)pp1)[rbase + 3];
    const f4 qx = {q0.x, q1.x, q2.x, q3.x};
    const f4 qy = {q0.y, q1.y, q2.y, q3.y};
    const f4 qz = {q0.z, q1.z, q2.z, q3.z};
    const f4 qw = {q0.w, q1.w, q2.w, q3.w};

    f4 sp = {0,0,0,0}, tA = {0,0,0,0}, sf = {0,0,0,0};
    const half8* fragv = (const half8*)fragB;
    const int jt0 = b * 256 + chunk * 16;
    const int j0g0 = b * NPTS + chunk * 256 + lr;    // lr = column
    const f4 zero = {0.f, 0.f, 0.f, 0.f};

#pragma unroll 4
    for (int t = 0; t < 16; ++t) {
        const half8 bfrag = fragv[(size_t)(jt0 + t) * 64 + l];   // contiguous
        const float4 pw = ((const float4*)pp2)[j0g0 + t * 16];
        const f4 cc = __builtin_amdgcn_mfma_f32_16x16x32_f16(afrag, bfrag, zero, 0, 0, 0);
        const f4 fd = cc - qw - pw.w;            // log2e * fea_dist2 (<=0)
        const f4 dx = qx - pw.x;
        const f4 dy = qy - pw.y;
        const f4 dz = qz - pw.z;
        const f4 s  = dx*dx + dy*dy + dz*dz;     // log2e * |dp|^2
        f4 ep, ef;
#pragma unroll
        for (int e = 0; e < 4; ++e) {
            ep[e] = __builtin_amdgcn_exp2f(-s[e]);
            ef[e] = __builtin_amdgcn_exp2f(fd[e]);
        }
        sp += ep;
        tA += ep * fd;
        sf += ef;
    }

    // reduce over the 16 columns (lane bits 0..3)
#pragma unroll
    for (int m = 1; m < 16; m <<= 1) {
#pragma unroll
        for (int e = 0; e < 4; ++e) {
            sp[e] += __shfl_xor(sp[e], m);
            tA[e] += __shfl_xor(tA[e], m);
            sf[e] += __shfl_xor(sf[e], m);
        }
    }
    if (lr == 0) {
#pragma unroll
        for (int e = 0; e < 4; ++e) {
            atomicAdd(&accS[rbase + e], sp[e]);
            atomicAdd(&accT[rbase + e], tA[e]);
            atomicAdd(&accF[rbase + e], sf[e]);
        }
    }
    __threadfence();
    __syncthreads();

    __shared__ int lastFlag;
    if (tid == 0) {
        unsigned old = __hip_atomic_fetch_add(&cnt[ig], 1u,
                        __ATOMIC_ACQ_REL, __HIP_MEMORY_SCOPE_AGENT);
        lastFlag = (old == NCHUNK - 1);
    }
    __syncthreads();
    if (!lastFlag) return;

    // ---- finalize this i-group's 64 rows ----
    if (tid < 64) {
        const int r = ig * 64 + tid;                 // rows are contiguous
        const int bb = r >> 12;
        const float sp_ = __hip_atomic_load(&accS[r], __ATOMIC_RELAXED, __HIP_MEMORY_SCOPE_AGENT);
        const float tp_ = __hip_atomic_load(&accT[r], __ATOMIC_RELAXED, __HIP_MEMORY_SCOPE_AGENT);
        const float sf_ = __hip_atomic_load(&accF[r], __ATOMIC_RELAXED, __HIP_MEMORY_SCOPE_AGENT);
        const float ce = __logf(sf_) - (tp_ * LN2) / sp_;
        float contrib = wg[r] * ce;

        const float4* a4 = (const float4*)(f1g + (size_t)r * DF);
        const float4* b4 = (const float4*)(f2g + (size_t)r * DF);
        float rr;
        {
            float4 a0 = a4[0], b0 = b4[0];
            rr = a0.w * a0.w + b0.w * b0.w;          // channel 3 only
        }
#pragma unroll
        for (int q = 1; q < 8; ++q) {
            float4 av = a4[q], bv = b4[q];
            rr += av.x*av.x + av.y*av.y + av.z*av.z + av.w*av.w;
            rr += bv.x*bv.x + bv.y*bv.y + bv.z*bv.z + bv.w*bv.w;
        }
#pragma unroll
        for (int off = 32; off > 0; off >>= 1) {
            contrib += __shfl_down(contrib, off);
            rr      += __shfl_down(rr, off);
        }
        if (tid == 0) {
            atomicAdd(&out[bb],     contrib);
            atomicAdd(&out[2 + bb], rr * (1.0f / (29.0f * (float)NPTS)));
        }
    }
}

extern "C" void kernel_launch(void* const* d_in, const int* in_sizes, int n_in,
                              void* d_out, int out_size, void* d_ws, size_t ws_size,
                              hipStream_t stream) {
    const float* pts = (const float*)d_in[0];
    const float* f1  = (const float*)d_in[1];
    const float* f2  = (const float*)d_in[2];
    const float* wg  = (const float*)d_in[3];
    float* out = (float*)d_out;

    float* ws = (float*)d_ws;
    float*     pp1   = ws;                           // 32768
    float*     pp2   = ws + 32768;                   // 32768
    _Float16*  fragB = (_Float16*)(ws + 65536);      // 262144 halves
    _Float16*  fragA = (_Float16*)(ws + 196608);     // 262144 halves
    float*     accS  = ws + 327680;                  // 8192
    float*     accT  = ws + 335872;                  // 8192
    float*     accF  = ws + 344064;                  // 8192
    unsigned*  cnt   = (unsigned*)(ws + 352256);     // 128

    kA_prep<<<ROWS_TOT / 64, 64, 0, stream>>>(pts, f1, f2, pp1, pp2,
                                              fragA, fragB, accS, accT, accF, cnt, out);
    kB_main<<<NGROUP * NCHUNK, 256, 0, stream>>>(pp1, pp2, fragA, fragB,
                                                 f1, f2, wg, accS, accT, accF, cnt, out);
}

// Round 5
// 37.064 us; speedup vs baseline: 4.8349x; 4.8349x over previous
//
#include <hip/hip_runtime.h>
#include <math.h>

// DeepFeatureLoss: B=2, N=4096, D=32, fp32 in/out.
// out[0..1] = ce_loss[b], out[2..3] = reg_loss[b].
//
// ce_i = log(s_f) - t/s_p   (softmax max pinned at 0; both dists <= 0):
//   s_p = sum_j exp(pd_ij), t = sum_j exp(pd_ij)*fd_ij, s_f = sum_j exp(fd_ij)
// exp2 folding: points *PSC, features *FSC, norms *L2E -> bare v_exp_f32;
// t is in log2 units -> *LN2 at finalize.
//
// R5 structure (no cross-block state, no fences):
//  kA: pack lane-ordered f16 fragments for f1 (A) and f2 (B); pp1/pp2 =
//      (p*PSC, n*L2E); regp[r] = sum_{ch>=3}(f1^2+f2^2); zero out.
//  kB: one block per 16-row i-tile (512 blocks x 512 threads). 8 waves
//      each cover 2 j-chunks (32 MFMA iters), wave shfl-reduce, LDS
//      combine across waves, 16-thread finalize -> 2 atomicAdds to out.
//
// ws (floats): pp1[0,32768) pp2[32768,65536) fragB[65536,196608)
// fragA[196608,327680) regp[327680,335872).

#define NPTS 4096
#define ROWS_TOT 8192
#define DF 32
#define NTILE 512                // 16-row i-tiles across both batches

#define L2E  1.4426950408889634f
#define LN2  0.6931471805599453f
#define FSC  1.6986436f          // sqrt(2*log2e)
#define PSC  240.2244f           // 200*sqrt(log2e)

typedef _Float16 half8 __attribute__((ext_vector_type(8)));
typedef float f4 __attribute__((ext_vector_type(4)));

// ---- kA: prep ----
__global__ void kA_prep(const float* __restrict__ pts,
                        const float* __restrict__ f1g,
                        const float* __restrict__ f2g,
                        float* __restrict__ pp1, float* __restrict__ pp2,
                        _Float16* __restrict__ fragA, _Float16* __restrict__ fragB,
                        float* __restrict__ regp, float* __restrict__ out) {
    const int r = blockIdx.x * 64 + threadIdx.x;     // 0..8191
    if (r < 4) out[r] = 0.0f;
    const int jt = r >> 4;                           // global tile id 0..511
    const int c  = r & 15;                           // row/col within tile

    float n1, n2, reg1, reg2;
    {
        const float4* f2v = (const float4*)(f2g + (size_t)r * DF);
        float vals[32];
        float s = 0.0f;
#pragma unroll
        for (int q = 0; q < 8; ++q) {
            float4 v = f2v[q];
            vals[4*q]=v.x; vals[4*q+1]=v.y; vals[4*q+2]=v.z; vals[4*q+3]=v.w;
            s += v.x*v.x + v.y*v.y + v.z*v.z + v.w*v.w;
        }
        n2 = s;
        reg2 = s - vals[0]*vals[0] - vals[1]*vals[1] - vals[2]*vals[2];
        half8* fv = (half8*)fragB;
#pragma unroll
        for (int kb = 0; kb < 4; ++kb) {             // lane-ordered slot
            half8 h;
#pragma unroll
            for (int i = 0; i < 8; ++i) h[i] = (_Float16)(vals[kb*8+i] * FSC);
            fv[(size_t)jt*64 + kb*16 + c] = h;
        }
    }
    {
        const float4* f1v = (const float4*)(f1g + (size_t)r * DF);
        float vals[32];
        float s = 0.0f;
#pragma unroll
        for (int q = 0; q < 8; ++q) {
            float4 v = f1v[q];
            vals[4*q]=v.x; vals[4*q+1]=v.y; vals[4*q+2]=v.z; vals[4*q+3]=v.w;
            s += v.x*v.x + v.y*v.y + v.z*v.z + v.w*v.w;
        }
        n1 = s;
        reg1 = s - vals[0]*vals[0] - vals[1]*vals[1] - vals[2]*vals[2];
        half8* fv = (half8*)fragA;
#pragma unroll
        for (int kb = 0; kb < 4; ++kb) {
            half8 h;
#pragma unroll
            for (int i = 0; i < 8; ++i) h[i] = (_Float16)(vals[kb*8+i] * FSC);
            fv[(size_t)jt*64 + kb*16 + c] = h;
        }
    }
    const float* pp = pts + (size_t)r * 3;
    const float px = pp[0]*PSC, py = pp[1]*PSC, pz = pp[2]*PSC;
    ((float4*)pp1)[r] = make_float4(px, py, pz, n1 * L2E);
    ((float4*)pp2)[r] = make_float4(px, py, pz, n2 * L2E);
    regp[r] = reg1 + reg2;
}

// ---- kB: one block per i-tile; 8 waves x 2 chunks; block-local combine ----
__launch_bounds__(512)
__global__ void kB_main(const float* __restrict__ pp1,
                        const float* __restrict__ pp2,
                        const _Float16* __restrict__ fragA,
                        const _Float16* __restrict__ fragB,
                        const float* __restrict__ regp,
                        const float* __restrict__ wg,
                        float* __restrict__ out) {
    __shared__ float sS[8][16], sT[8][16], sF[8][16];

    const int tid = threadIdx.x;
    const int l = tid & 63, wv = tid >> 6;           // wave 0..7
    const int i_tile = blockIdx.x;                   // 0..511
    const int b = i_tile >> 8;
    const int i0g = i_tile * 16;                     // global row base
    const int lr = l & 15, lk = l >> 4;

    const half8 afrag = ((const half8*)fragA)[(size_t)i_tile * 64 + l];

    const int rbase = i0g + lk * 4;                  // this lane's 4 rows
    const float4 q0 = ((const float4*)pp1)[rbase + 0];
    const float4 q1 = ((const float4*)pp1)[rbase + 1];
    const float4 q2 = ((const float4*)pp1)[rbase + 2];
    const float4 q3 = ((const float4*)pp1)[rbase + 3];
    const f4 qx = {q0.x, q1.x, q2.x, q3.x};
    const f4 qy = {q0.y, q1.y, q2.y, q3.y};
    const f4 qz = {q0.z, q1.z, q2.z, q3.z};
    const f4 qw = {q0.w, q1.w, q2.w, q3.w};

    f4 sp = {0,0,0,0}, tA = {0,0,0,0}, sf = {0,0,0,0};
    const half8* fragv = (const half8*)fragB;
    const f4 zero = {0.f, 0.f, 0.f, 0.f};

#pragma unroll
    for (int cc = 0; cc < 2; ++cc) {
        const int chunk = wv * 2 + cc;               // 0..15
        const int jt0 = b * 256 + chunk * 16;
        const int j0g0 = b * NPTS + chunk * 256 + lr;
#pragma unroll 4
        for (int t = 0; t < 16; ++t) {
            const half8 bfrag = fragv[(size_t)(jt0 + t) * 64 + l];
            const float4 pw = ((const float4*)pp2)[j0g0 + t * 16];
            const f4 cc4 = __builtin_amdgcn_mfma_f32_16x16x32_f16(afrag, bfrag, zero, 0, 0, 0);
            const f4 fd = cc4 - qw - pw.w;           // log2e * fea_dist2 (<=0)
            const f4 dx = qx - pw.x;
            const f4 dy = qy - pw.y;
            const f4 dz = qz - pw.z;
            const f4 s  = dx*dx + dy*dy + dz*dz;     // log2e * |dp|^2
            f4 ep, ef;
#pragma unroll
            for (int e = 0; e < 4; ++e) {
                ep[e] = __builtin_amdgcn_exp2f(-s[e]);
                ef[e] = __builtin_amdgcn_exp2f(fd[e]);
            }
            sp += ep;
            tA += ep * fd;
            sf += ef;
        }
    }

    // reduce over the 16 columns (lane bits 0..3)
#pragma unroll
    for (int m = 1; m < 16; m <<= 1) {
#pragma unroll
        for (int e = 0; e < 4; ++e) {
            sp[e] += __shfl_xor(sp[e], m);
            tA[e] += __shfl_xor(tA[e], m);
            sf[e] += __shfl_xor(sf[e], m);
        }
    }
    if (lr == 0) {
#pragma unroll
        for (int e = 0; e < 4; ++e) {
            sS[wv][lk * 4 + e] = sp[e];
            sT[wv][lk * 4 + e] = tA[e];
            sF[wv][lk * 4 + e] = sf[e];
        }
    }
    __syncthreads();

    if (tid < 16) {
        float sp_ = 0.f, tp_ = 0.f, sf_ = 0.f;
#pragma unroll
        for (int w = 0; w < 8; ++w) {
            sp_ += sS[w][tid];
            tp_ += sT[w][tid];
            sf_ += sF[w][tid];
        }
        const int r = i0g + tid;
        const float ce = __logf(sf_) - (tp_ * LN2) / sp_;
        float contrib = wg[r] * ce;
        float rr = regp[r];
#pragma unroll
        for (int m = 1; m < 16; m <<= 1) {           // lanes 0..15 only
            contrib += __shfl_xor(contrib, m);
            rr      += __shfl_xor(rr, m);
        }
        if (tid == 0) {
            atomicAdd(&out[b],     contrib);
            atomicAdd(&out[2 + b], rr * (1.0f / (29.0f * (float)NPTS)));
        }
    }
}

extern "C" void kernel_launch(void* const* d_in, const int* in_sizes, int n_in,
                              void* d_out, int out_size, void* d_ws, size_t ws_size,
                              hipStream_t stream) {
    const float* pts = (const float*)d_in[0];
    const float* f1  = (const float*)d_in[1];
    const float* f2  = (const float*)d_in[2];
    const float* wg  = (const float*)d_in[3];
    float* out = (float*)d_out;

    float* ws = (float*)d_ws;
    float*     pp1   = ws;                           // 32768
    float*     pp2   = ws + 32768;                   // 32768
    _Float16*  fragB = (_Float16*)(ws + 65536);      // 262144 halves
    _Float16*  fragA = (_Float16*)(ws + 196608);     // 262144 halves
    float*     regp  = ws + 327680;                  // 8192

    kA_prep<<<ROWS_TOT / 64, 64, 0, stream>>>(pts, f1, f2, pp1, pp2,
                                              fragA, fragB, regp, out);
    kB_main<<<NTILE, 512, 0, stream>>>(pp1, pp2, fragA, fragB, regp, wg, out);
}

// Round 6
// 33.015 us; speedup vs baseline: 5.4278x; 1.1226x over previous
//
#include <hip/hip_runtime.h>
#include <math.h>

// DeepFeatureLoss: B=2, N=4096, D=32, fp32 in/out.
// out[0..1] = ce_loss[b], out[2..3] = reg_loss[b].
//
// ce_i = log(s_f) - t/s_p   (softmax max pinned at 0; both dists <= 0):
//   s_p = sum_j exp(pd_ij), t = sum_j exp(pd_ij)*fd_ij, s_f = sum_j exp(fd_ij)
// exp2 folding: points *PSC, features *FSC, norms *L2E -> bare v_exp_f32;
// t is in log2 units -> *LN2 at finalize.
//
// R6: kB inner loop flattened to 32 iters (indices linear in t) with
// explicit 2-deep register prefetch of bfrag/pw and full unroll —
// R2..R5 evidence says this kernel is latency-bound ~4x above its
// VALU floor (R4: VALUBusy 6.7%; VGPR 40 = no pipelining).
//
// ws (floats): pp1[0,32768) pp2[32768,65536) fragB[65536,196608)
// fragA[196608,327680) regp[327680,335872).

#define NPTS 4096
#define ROWS_TOT 8192
#define DF 32
#define NTILE 512                // 16-row i-tiles across both batches

#define L2E  1.4426950408889634f
#define LN2  0.6931471805599453f
#define FSC  1.6986436f          // sqrt(2*log2e)
#define PSC  240.2244f           // 200*sqrt(log2e)

typedef _Float16 half8 __attribute__((ext_vector_type(8)));
typedef float f4 __attribute__((ext_vector_type(4)));

// ---- kA: prep ----
__global__ void kA_prep(const float* __restrict__ pts,
                        const float* __restrict__ f1g,
                        const float* __restrict__ f2g,
                        float* __restrict__ pp1, float* __restrict__ pp2,
                        _Float16* __restrict__ fragA, _Float16* __restrict__ fragB,
                        float* __restrict__ regp, float* __restrict__ out) {
    const int r = blockIdx.x * 64 + threadIdx.x;     // 0..8191
    if (r < 4) out[r] = 0.0f;
    const int jt = r >> 4;                           // global tile id 0..511
    const int c  = r & 15;                           // row/col within tile

    float n1, n2, reg1, reg2;
    {
        const float4* f2v = (const float4*)(f2g + (size_t)r * DF);
        float vals[32];
        float s = 0.0f;
#pragma unroll
        for (int q = 0; q < 8; ++q) {
            float4 v = f2v[q];
            vals[4*q]=v.x; vals[4*q+1]=v.y; vals[4*q+2]=v.z; vals[4*q+3]=v.w;
            s += v.x*v.x + v.y*v.y + v.z*v.z + v.w*v.w;
        }
        n2 = s;
        reg2 = s - vals[0]*vals[0] - vals[1]*vals[1] - vals[2]*vals[2];
        half8* fv = (half8*)fragB;
#pragma unroll
        for (int kb = 0; kb < 4; ++kb) {             // lane-ordered slot
            half8 h;
#pragma unroll
            for (int i = 0; i < 8; ++i) h[i] = (_Float16)(vals[kb*8+i] * FSC);
            fv[(size_t)jt*64 + kb*16 + c] = h;
        }
    }
    {
        const float4* f1v = (const float4*)(f1g + (size_t)r * DF);
        float vals[32];
        float s = 0.0f;
#pragma unroll
        for (int q = 0; q < 8; ++q) {
            float4 v = f1v[q];
            vals[4*q]=v.x; vals[4*q+1]=v.y; vals[4*q+2]=v.z; vals[4*q+3]=v.w;
            s += v.x*v.x + v.y*v.y + v.z*v.z + v.w*v.w;
        }
        n1 = s;
        reg1 = s - vals[0]*vals[0] - vals[1]*vals[1] - vals[2]*vals[2];
        half8* fv = (half8*)fragA;
#pragma unroll
        for (int kb = 0; kb < 4; ++kb) {
            half8 h;
#pragma unroll
            for (int i = 0; i < 8; ++i) h[i] = (_Float16)(vals[kb*8+i] * FSC);
            fv[(size_t)jt*64 + kb*16 + c] = h;
        }
    }
    const float* pp = pts + (size_t)r * 3;
    const float px = pp[0]*PSC, py = pp[1]*PSC, pz = pp[2]*PSC;
    ((float4*)pp1)[r] = make_float4(px, py, pz, n1 * L2E);
    ((float4*)pp2)[r] = make_float4(px, py, pz, n2 * L2E);
    regp[r] = reg1 + reg2;
}

// ---- kB: one block per i-tile; 8 waves x 32 j-tiles; prefetched loop ----
__launch_bounds__(512)
__global__ void kB_main(const float* __restrict__ pp1,
                        const float* __restrict__ pp2,
                        const _Float16* __restrict__ fragA,
                        const _Float16* __restrict__ fragB,
                        const float* __restrict__ regp,
                        const float* __restrict__ wg,
                        float* __restrict__ out) {
    __shared__ float sS[8][16], sT[8][16], sF[8][16];

    const int tid = threadIdx.x;
    const int l = tid & 63, wv = tid >> 6;           // wave 0..7
    const int i_tile = blockIdx.x;                   // 0..511
    const int b = i_tile >> 8;
    const int i0g = i_tile * 16;                     // global row base
    const int lr = l & 15, lk = l >> 4;

    const half8 afrag = ((const half8*)fragA)[(size_t)i_tile * 64 + l];

    const int rbase = i0g + lk * 4;                  // this lane's 4 rows
    const float4 q0 = ((const float4*)pp1)[rbase + 0];
    const float4 q1 = ((const float4*)pp1)[rbase + 1];
    const float4 q2 = ((const float4*)pp1)[rbase + 2];
    const float4 q3 = ((const float4*)pp1)[rbase + 3];
    const f4 qx = {q0.x, q1.x, q2.x, q3.x};
    const f4 qy = {q0.y, q1.y, q2.y, q3.y};
    const f4 qz = {q0.z, q1.z, q2.z, q3.z};
    const f4 qw = {q0.w, q1.w, q2.w, q3.w};

    // wave's j range is linear: frag tile (b*256 + wv*32 + t), rows
    // b*4096 + wv*512 + t*16 + lr  -- both strides constant in t.
    const half8*  fbase = (const half8*)fragB + ((size_t)(b * 256 + wv * 32) * 64 + l);
    const float4* pbase = (const float4*)pp2 + (b * NPTS + wv * 512 + lr);

    f4 sp = {0,0,0,0}, tA = {0,0,0,0}, sf = {0,0,0,0};
    const f4 zero = {0.f, 0.f, 0.f, 0.f};

    half8  bfA = fbase[0];
    float4 pwA = pbase[0];
#pragma unroll
    for (int t = 0; t < 32; ++t) {
        half8  bfN = bfA;
        float4 pwN = pwA;
        if (t < 31) {                                // prefetch next iter
            bfN = fbase[(t + 1) * 64];
            pwN = pbase[(t + 1) * 16];
        }
        const f4 cc4 = __builtin_amdgcn_mfma_f32_16x16x32_f16(afrag, bfA, zero, 0, 0, 0);
        const f4 fd = cc4 - qw - pwA.w;              // log2e * fea_dist2 (<=0)
        const f4 dx = qx - pwA.x;
        const f4 dy = qy - pwA.y;
        const f4 dz = qz - pwA.z;
        const f4 s  = dx*dx + dy*dy + dz*dz;         // log2e * |dp|^2
        f4 ep, ef;
#pragma unroll
        for (int e = 0; e < 4; ++e) {
            ep[e] = __builtin_amdgcn_exp2f(-s[e]);
            ef[e] = __builtin_amdgcn_exp2f(fd[e]);
        }
        sp += ep;
        tA += ep * fd;
        sf += ef;
        bfA = bfN;
        pwA = pwN;
    }

    // reduce over the 16 columns (lane bits 0..3)
#pragma unroll
    for (int m = 1; m < 16; m <<= 1) {
#pragma unroll
        for (int e = 0; e < 4; ++e) {
            sp[e] += __shfl_xor(sp[e], m);
            tA[e] += __shfl_xor(tA[e], m);
            sf[e] += __shfl_xor(sf[e], m);
        }
    }
    if (lr == 0) {
#pragma unroll
        for (int e = 0; e < 4; ++e) {
            sS[wv][lk * 4 + e] = sp[e];
            sT[wv][lk * 4 + e] = tA[e];
            sF[wv][lk * 4 + e] = sf[e];
        }
    }
    __syncthreads();

    if (tid < 16) {
        float sp_ = 0.f, tp_ = 0.f, sf_ = 0.f;
#pragma unroll
        for (int w = 0; w < 8; ++w) {
            sp_ += sS[w][tid];
            tp_ += sT[w][tid];
            sf_ += sF[w][tid];
        }
        const int r = i0g + tid;
        const float ce = __logf(sf_) - (tp_ * LN2) / sp_;
        float contrib = wg[r] * ce;
        float rr = regp[r];
#pragma unroll
        for (int m = 1; m < 16; m <<= 1) {           // lanes 0..15 only
            contrib += __shfl_xor(contrib, m);
            rr      += __shfl_xor(rr, m);
        }
        if (tid == 0) {
            atomicAdd(&out[b],     contrib);
            atomicAdd(&out[2 + b], rr * (1.0f / (29.0f * (float)NPTS)));
        }
    }
}

extern "C" void kernel_launch(void* const* d_in, const int* in_sizes, int n_in,
                              void* d_out, int out_size, void* d_ws, size_t ws_size,
                              hipStream_t stream) {
    const float* pts = (const float*)d_in[0];
    const float* f1  = (const float*)d_in[1];
    const float* f2  = (const float*)d_in[2];
    const float* wg  = (const float*)d_in[3];
    float* out = (float*)d_out;

    float* ws = (float*)d_ws;
    float*     pp1   = ws;                           // 32768
    float*     pp2   = ws + 32768;                   // 32768
    _Float16*  fragB = (_Float16*)(ws + 65536);      // 262144 halves
    _Float16*  fragA = (_Float16*)(ws + 196608);     // 262144 halves
    float*     regp  = ws + 327680;                  // 8192

    kA_prep<<<ROWS_TOT / 64, 64, 0, stream>>>(pts, f1, f2, pp1, pp2,
                                              fragA, fragB, regp, out);
    kB_main<<<NTILE, 512, 0, stream>>>(pp1, pp2, fragA, fragB, regp, wg, out);
}